// Round 3
// baseline (826.873 us; speedup 1.0000x reference)
//
#include <hip/hip_runtime.h>
#include <cstdint>
#include <cstddef>

typedef __bf16 bf16;
typedef __bf16 bf16x8 __attribute__((ext_vector_type(8)));
typedef float f32x4 __attribute__((ext_vector_type(4)));

#define BDIM 4
#define TDIM 2048
#define DDIM 2048
#define HDIM 8
#define DHD 256
#define MTOT 8192
#define NCHUNK 64
#define LCHUNK 32

// ---- dtype-polymorphic load/store helpers ----------------------------------
__device__ __forceinline__ bf16x8 load8(const bf16* p) { return *(const bf16x8*)p; }
__device__ __forceinline__ bf16x8 load8(const float* p) {
  const float4 a = *(const float4*)p;
  const float4 b = *(const float4*)(p + 4);
  bf16x8 r;
  r[0] = (bf16)a.x; r[1] = (bf16)a.y; r[2] = (bf16)a.z; r[3] = (bf16)a.w;
  r[4] = (bf16)b.x; r[5] = (bf16)b.y; r[6] = (bf16)b.z; r[7] = (bf16)b.w;
  return r;
}
__device__ __forceinline__ float ld1(const bf16* p) { return (float)*p; }
__device__ __forceinline__ float ld1(const float* p) { return *p; }
__device__ __forceinline__ void st1(bf16* p, float v) { *p = (bf16)v; }
__device__ __forceinline__ void st1(float* p, float v) { *p = v; }

__device__ __forceinline__ float gelu_tanh(float v) {
  return 0.5f * v * (1.f + tanhf(0.7978845608028654f * (v + 0.044715f * v * v * v)));
}

// ---------------------------------------------------------------------------
// dtype detector: reads first 256 half-words of x. If tensors are bf16,
// nearly all have exponent fields of ~N(0,1) values (exp in [0x6B,0x83]).
// If tensors are fp32, the low half-words have uniform-random exponents
// (~55% sane overall). flag: 0 = bf16, 1 = fp32.
// ---------------------------------------------------------------------------
__global__ void detect_kernel(const unsigned short* __restrict__ xr, int* __restrict__ flag) {
  if (threadIdx.x == 0 && blockIdx.x == 0) {
    int sane = 0;
    for (int i = 0; i < 256; ++i) {
      int e = (xr[i] >> 7) & 0xFF;
      if (e >= 0x6B && e <= 0x83) ++sane;
    }
    *flag = (sane >= 224) ? 0 : 1;
  }
}

// ---------------------------------------------------------------------------
// C[m,n] = epi(sum_k A[m,k]*B[n,k] + bias[n]); fp32 accum, 128x128 tile,
// BK=32, 4 waves 2x2, 16x16x32 bf16 MFMA, register-staged LDS + prefetch.
// EPI: 0 = bias; 1 = bias+gelu; 2 = bias+gelu then * hmul[m*ldc+n]
// (hmul may alias C: each cell is read and written only by its own lane).
// ---------------------------------------------------------------------------
template <typename TA, typename TB, typename TO, int EPI>
__global__ __launch_bounds__(256) void gemm_bt(
    const int* __restrict__ flag, int want,
    const TA* __restrict__ A, const TB* __restrict__ Bm,
    const TB* __restrict__ bias, TO* __restrict__ C,
    const bf16* __restrict__ hmul,
    int K, int lda, int ldb, int ldc) {
  if (*flag != want) return;
  const int n0 = blockIdx.x * 128;
  const int m0 = blockIdx.y * 128;
  __shared__ bf16 As[128 * 32];
  __shared__ bf16 Bs[128 * 32];
  const int tid = threadIdx.x;
  const int lane = tid & 63;
  const int wid = tid >> 6;
  const int waveM = wid >> 1, waveN = wid & 1;
  const int quad = lane >> 4;
  const int l15 = lane & 15;
  const int r0 = tid >> 2;
  const int cs = (tid & 3) * 8;

  const TA* Ar0 = A + (size_t)(m0 + r0) * lda + cs;
  const TA* Ar1 = A + (size_t)(m0 + r0 + 64) * lda + cs;
  const TB* Br0 = Bm + (size_t)(n0 + r0) * ldb + cs;
  const TB* Br1 = Bm + (size_t)(n0 + r0 + 64) * ldb + cs;

  f32x4 acc[4][4];
#pragma unroll
  for (int i = 0; i < 4; ++i)
#pragma unroll
    for (int j = 0; j < 4; ++j)
#pragma unroll
      for (int r = 0; r < 4; ++r) acc[i][j][r] = 0.f;

  bf16x8 ga0 = load8(Ar0), ga1 = load8(Ar1);
  bf16x8 gb0 = load8(Br0), gb1 = load8(Br1);

  for (int k0 = 0; k0 < K; k0 += 32) {
    if (k0) __syncthreads();
    *(bf16x8*)&As[r0 * 32 + cs] = ga0;
    *(bf16x8*)&As[(r0 + 64) * 32 + cs] = ga1;
    *(bf16x8*)&Bs[r0 * 32 + cs] = gb0;
    *(bf16x8*)&Bs[(r0 + 64) * 32 + cs] = gb1;
    const int kn = k0 + 32;
    if (kn < K) {
      ga0 = load8(Ar0 + kn); ga1 = load8(Ar1 + kn);
      gb0 = load8(Br0 + kn); gb1 = load8(Br1 + kn);
    }
    __syncthreads();
    bf16x8 af[4], bfr[4];
#pragma unroll
    for (int i = 0; i < 4; ++i) {
      af[i]  = *(const bf16x8*)&As[(waveM * 64 + i * 16 + l15) * 32 + quad * 8];
      bfr[i] = *(const bf16x8*)&Bs[(waveN * 64 + i * 16 + l15) * 32 + quad * 8];
    }
#pragma unroll
    for (int i = 0; i < 4; ++i)
#pragma unroll
      for (int j = 0; j < 4; ++j)
        acc[i][j] = __builtin_amdgcn_mfma_f32_16x16x32_bf16(af[i], bfr[j], acc[i][j], 0, 0, 0);
  }

#pragma unroll
  for (int j = 0; j < 4; ++j) {
    const int n = n0 + waveN * 64 + j * 16 + l15;
    const float bv = ld1(bias + n);
#pragma unroll
    for (int i = 0; i < 4; ++i) {
#pragma unroll
      for (int r = 0; r < 4; ++r) {
        const int m = m0 + waveM * 64 + i * 16 + quad * 4 + r;
        float v = acc[i][j][r] + bv;
        if (EPI >= 1) v = gelu_tanh(v);
        if (EPI == 2) v *= (float)hmul[(size_t)m * ldc + n];
        st1(C + (size_t)m * ldc + n, v);
      }
    }
  }
}

// ---------------------------------------------------------------------------
// depthwise causal conv, TW=4; xp (bf16 scratch) -> xc (bf16 scratch)
// ---------------------------------------------------------------------------
template <typename T>
__global__ __launch_bounds__(256) void conv_kernel(
    const int* __restrict__ flag, int want,
    const bf16* __restrict__ xp, const T* __restrict__ cw,
    const T* __restrict__ cb, const int* __restrict__ segp,
    bf16* __restrict__ xc) {
  if (*flag != want) return;
  int v = blockIdx.x * 256 + threadIdx.x;
  int dv = v & (DDIM / 8 - 1);
  int m = v >> 8;
  int d0 = dv * 8;
  int t = m & (TDIM - 1);
  int sp = segp[m];
  float acc[8];
  bf16x8 bb = load8(cb + d0);
#pragma unroll
  for (int j = 0; j < 8; ++j) acc[j] = (float)bb[j];
#pragma unroll
  for (int i = 0; i < 4; ++i) {
    int shift = 3 - i;
    if (t >= shift && sp >= shift) {
      bf16x8 xv = *(const bf16x8*)&xp[(size_t)(m - shift) * DDIM + d0];
      bf16x8 wv = load8(cw + i * DDIM + d0);
#pragma unroll
      for (int j = 0; j < 8; ++j) acc[j] = fmaf((float)xv[j], (float)wv[j], acc[j]);
    }
  }
  bf16x8 o;
#pragma unroll
  for (int j = 0; j < 8; ++j) o[j] = (bf16)acc[j];
  *(bf16x8*)&xc[(size_t)m * DDIM + d0] = o;
}

// ---------------------------------------------------------------------------
// transpose gate weights into bf16 scratch: dst[h][j][i] = src[h][i][j]
// ---------------------------------------------------------------------------
template <typename T>
__global__ __launch_bounds__(256) void transpose_gates(
    const int* __restrict__ flag, int want,
    const T* __restrict__ gxw, const T* __restrict__ gaw,
    bf16* __restrict__ gxT, bf16* __restrict__ gaT) {
  if (*flag != want) return;
  __shared__ bf16 tile[32][33];
  int zz = blockIdx.z;
  int h = zz >> 1;
  const T* src = (zz & 1) ? gaw : gxw;
  bf16* dst = (zz & 1) ? gaT : gxT;
  int j0 = blockIdx.x * 32;
  int i0 = blockIdx.y * 32;
  int r = threadIdx.x >> 5;
  int c = threadIdx.x & 31;
  for (int rr = r; rr < 32; rr += 8)
    tile[rr][c] = (bf16)ld1(&src[(size_t)(h * DHD + i0 + rr) * DHD + j0 + c]);
  __syncthreads();
  for (int rr = r; rr < 32; rr += 8)
    dst[(size_t)(h * DHD + j0 + rr) * DHD + i0 + c] = tile[c][rr];
}

// ---------------------------------------------------------------------------
// fused gate GEMMs (both gates) + RG-LRU epilogue. Tiles: M=128 x N=256
// (full head) so `nrm` can be written IN-PLACE over xconv: block (m0,h)
// exclusively owns rows m0..m0+127 x cols of head h. 512 threads, 8 waves
// (2 M x 4 N). loga -> W1 (xproj slot, dead). K = DH = 256.
// ---------------------------------------------------------------------------
template <typename T>
__global__ __launch_bounds__(512) void gate_kernel(
    const int* __restrict__ flag, int want,
    const bf16* __restrict__ xconv,   // [M,D] scratch (= d_out)
    const bf16* __restrict__ gxT, const bf16* __restrict__ gaT,
    const T* __restrict__ gxb, const T* __restrict__ gab,
    const T* __restrict__ apar, const int* __restrict__ segp,
    bf16* __restrict__ loga,          // [M,D] -> W1
    bf16* __restrict__ nrm) {         // [M,D] in-place over xconv
  if (*flag != want) return;
  const int m0 = blockIdx.x * 128;
  const int h = blockIdx.y;
  __shared__ bf16 As[128 * 32];
  __shared__ bf16 Bx[256 * 32];
  __shared__ bf16 Ba[256 * 32];
  const int tid = threadIdx.x;
  const int lane = tid & 63;
  const int wid = tid >> 6;           // 0..7
  const int waveM = wid >> 2, waveN = wid & 3;
  const int quad = lane >> 4;
  const int l15 = lane & 15;
  const int r0 = tid >> 2;            // 0..127
  const int cs = (tid & 3) * 8;

  const bf16* baseA = xconv + (size_t)(m0 + r0) * DDIM + h * DHD + cs;
  const bf16* baseX = gxT + (size_t)h * DHD * DHD + cs;
  const bf16* baseB = gaT + (size_t)h * DHD * DHD + cs;

  f32x4 accx[4][4], acca[4][4];
#pragma unroll
  for (int i = 0; i < 4; ++i)
#pragma unroll
    for (int j = 0; j < 4; ++j)
#pragma unroll
      for (int r = 0; r < 4; ++r) { accx[i][j][r] = 0.f; acca[i][j][r] = 0.f; }

  bf16x8 gA, gX0, gX1, gB0, gB1;
#define GATE_LOAD(kk)                                                     \
  do {                                                                    \
    gA  = *(const bf16x8*)&baseA[(kk)];                                   \
    gX0 = *(const bf16x8*)&baseX[(size_t)r0 * DHD + (kk)];                \
    gX1 = *(const bf16x8*)&baseX[(size_t)(r0 + 128) * DHD + (kk)];        \
    gB0 = *(const bf16x8*)&baseB[(size_t)r0 * DHD + (kk)];                \
    gB1 = *(const bf16x8*)&baseB[(size_t)(r0 + 128) * DHD + (kk)];        \
  } while (0)

  GATE_LOAD(0);
  for (int k0 = 0; k0 < DHD; k0 += 32) {
    if (k0) __syncthreads();
    *(bf16x8*)&As[r0 * 32 + cs] = gA;
    *(bf16x8*)&Bx[r0 * 32 + cs] = gX0;
    *(bf16x8*)&Bx[(r0 + 128) * 32 + cs] = gX1;
    *(bf16x8*)&Ba[r0 * 32 + cs] = gB0;
    *(bf16x8*)&Ba[(r0 + 128) * 32 + cs] = gB1;
    const int kn = k0 + 32;
    if (kn < DHD) GATE_LOAD(kn);
    __syncthreads();
    bf16x8 af[4];
#pragma unroll
    for (int i = 0; i < 4; ++i)
      af[i] = *(const bf16x8*)&As[(waveM * 64 + i * 16 + l15) * 32 + quad * 8];
#pragma unroll
    for (int j = 0; j < 4; ++j) {
      bf16x8 bx = *(const bf16x8*)&Bx[(waveN * 64 + j * 16 + l15) * 32 + quad * 8];
      bf16x8 ba = *(const bf16x8*)&Ba[(waveN * 64 + j * 16 + l15) * 32 + quad * 8];
#pragma unroll
      for (int i = 0; i < 4; ++i) {
        accx[i][j] = __builtin_amdgcn_mfma_f32_16x16x32_bf16(af[i], bx, accx[i][j], 0, 0, 0);
        acca[i][j] = __builtin_amdgcn_mfma_f32_16x16x32_bf16(af[i], ba, acca[i][j], 0, 0, 0);
      }
    }
  }
#undef GATE_LOAD

#pragma unroll
  for (int j = 0; j < 4; ++j) {
    const int jj = waveN * 64 + j * 16 + l15;   // 0..255 within head
    const int d = h * DHD + jj;
    const float bxv = ld1(gxb + h * DHD + jj);
    const float bav = ld1(gab + h * DHD + jj);
    const float sp = log1pf(expf(ld1(apar + d)));   // softplus(a_param)
#pragma unroll
    for (int i = 0; i < 4; ++i) {
#pragma unroll
      for (int r = 0; r < 4; ++r) {
        const int m = m0 + waveM * 64 + i * 16 + quad * 4 + r;
        const float gx = 1.f / (1.f + expf(-(accx[i][j][r] + bxv)));
        const float ga = 1.f / (1.f + expf(-(acca[i][j][r] + bav)));
        const float log_a = -8.f * ga * sp;
        const bool reset = (segp[m] == 0);
        const float mult = reset ? 1.f : sqrtf(fmaxf(1.f - expf(2.f * log_a), 0.f));
        const float xc = (float)xconv[(size_t)m * DDIM + d];
        nrm[(size_t)m * DDIM + d] = (bf16)(xc * gx * mult);
        loga[(size_t)m * DDIM + d] = reset ? (bf16)(-__builtin_inff()) : (bf16)log_a;
      }
    }
  }
}

// ---------------------------------------------------------------------------
// chunked linear scan: h[t] = exp(loga[t])*h[t-1] + nrm[t]
// ---------------------------------------------------------------------------
__global__ __launch_bounds__(256) void scan_phase1(
    const bf16* __restrict__ loga, const bf16* __restrict__ nrm,
    float* __restrict__ chA, float* __restrict__ chH) {
  int idx = blockIdx.x * 256 + threadIdx.x;
  int d = idx & (DDIM - 1);
  int c = (idx >> 11) & (NCHUNK - 1);
  int b = idx >> 17;
  size_t base = (size_t)(b * TDIM + c * LCHUNK) * DDIM + d;
  float A = 1.f, hh = 0.f;
#pragma unroll 4
  for (int i = 0; i < LCHUNK; ++i) {
    size_t o = base + (size_t)i * DDIM;
    float a = expf((float)loga[o]);
    hh = fmaf(a, hh, (float)nrm[o]);
    A *= a;
  }
  int ci = (b * NCHUNK + c) * DDIM + d;
  chA[ci] = A;
  chH[ci] = hh;
}

__global__ __launch_bounds__(256) void scan_phase2(
    const float* __restrict__ chA, const float* __restrict__ chH,
    float* __restrict__ hst) {
  int idx = blockIdx.x * 256 + threadIdx.x;
  int d = idx & (DDIM - 1);
  int b = idx >> 11;
  float s = 0.f;
  for (int c = 0; c < NCHUNK; ++c) {
    int ci = (b * NCHUNK + c) * DDIM + d;
    hst[ci] = s;
    s = fmaf(chA[ci], s, chH[ci]);
  }
}

// writes h in-place over loga (same-index elementwise, exclusive per thread)
__global__ __launch_bounds__(256) void scan_phase3(
    bf16* __restrict__ loga, const bf16* __restrict__ nrm,
    const float* __restrict__ hst) {
  int idx = blockIdx.x * 256 + threadIdx.x;
  int d = idx & (DDIM - 1);
  int c = (idx >> 11) & (NCHUNK - 1);
  int b = idx >> 17;
  size_t base = (size_t)(b * TDIM + c * LCHUNK) * DDIM + d;
  float hh = hst[(b * NCHUNK + c) * DDIM + d];
#pragma unroll 4
  for (int i = 0; i < LCHUNK; ++i) {
    size_t o = base + (size_t)i * DDIM;
    float a = expf((float)loga[o]);
    hh = fmaf(a, hh, (float)nrm[o]);
    loga[o] = (bf16)hh;
  }
}

// ---------------------------------------------------------------------------
extern "C" void kernel_launch(void* const* d_in, const int* in_sizes, int n_in,
                              void* d_out, int out_size, void* d_ws, size_t ws_size,
                              hipStream_t stream) {
  // Workspace (~40.2 MiB): flag | chA | chH | hst | gxT | gaT | W1[M,D]bf16
  char* ws = (char*)d_ws;
  const size_t CH = (size_t)BDIM * NCHUNK * DDIM * 4;   // 2 MiB
  const size_t GW = (size_t)HDIM * DHD * DHD * 2;       // 1 MiB
  int*   flag = (int*)ws;
  float* chA  = (float*)(ws + 256);
  float* chH  = (float*)(ws + 256 + CH);
  float* hst  = (float*)(ws + 256 + 2 * CH);
  bf16*  gxT  = (bf16*)(ws + 256 + 3 * CH);
  bf16*  gaT  = (bf16*)(ws + 256 + 3 * CH + GW);
  bf16*  W1   = (bf16*)(ws + 256 + 3 * CH + 2 * GW);    // 32 MiB
  bf16*  O    = (bf16*)d_out;                            // scratch: xconv/nrm

  dim3 blk(256);
  detect_kernel<<<1, 64, 0, stream>>>((const unsigned short*)d_in[0], flag);

  // dual-dtype launches: want=0 (bf16) and want=1 (fp32); loser exits early.
#define DUAL(T, W)                                                            \
  {                                                                           \
    const T* x    = (const T*)d_in[0];                                        \
    const T* Wy   = (const T*)d_in[2];                                        \
    const T* by   = (const T*)d_in[3];                                        \
    const T* Wx   = (const T*)d_in[4];                                        \
    const T* bx   = (const T*)d_in[5];                                        \
    const T* cw   = (const T*)d_in[6];                                        \
    const T* cb   = (const T*)d_in[7];                                        \
    const T* gxw  = (const T*)d_in[8];                                        \
    const T* gxb  = (const T*)d_in[9];                                        \
    const T* gaw  = (const T*)d_in[10];                                       \
    const T* gab  = (const T*)d_in[11];                                       \
    const T* apar = (const T*)d_in[12];                                       \
    const int* segp = (const int*)d_in[1];                                    \
    transpose_gates<T><<<dim3(8, 8, 16), blk, 0, stream>>>(flag, W, gxw, gaw, gxT, gaT); \
    gemm_bt<T, T, bf16, 0><<<dim3(16, 64), blk, 0, stream>>>(                 \
        flag, W, x, Wx, bx, W1, nullptr, DDIM, DDIM, DDIM, DDIM);             \
    conv_kernel<T><<<dim3(MTOT * (DDIM / 8) / 256), blk, 0, stream>>>(        \
        flag, W, W1, cw, cb, segp, O);                                        \
    gate_kernel<T><<<dim3(64, 8), dim3(512), 0, stream>>>(                    \
        flag, W, O, gxT, gaT, gxb, gab, apar, segp, W1, O);                   \
  }
  DUAL(bf16, 0)
  DUAL(float, 1)
#undef DUAL

  scan_phase1<<<dim3(BDIM * NCHUNK * DDIM / 256), blk, 0, stream>>>(W1, O, chA, chH);
  scan_phase2<<<dim3(BDIM * DDIM / 256), blk, 0, stream>>>(chA, chH, hst);
  scan_phase3<<<dim3(BDIM * NCHUNK * DDIM / 256), blk, 0, stream>>>(W1, O, hst);
  // W1 now holds h = x_lru

  // z = h * gelu(x@Wy^T + by) -> W1 in-place (hmul aliases C, per-cell safe)
  gemm_bt<bf16, bf16, bf16, 2><<<dim3(16, 64), blk, 0, stream>>>(
      flag, 0, (const bf16*)d_in[0], (const bf16*)d_in[2], (const bf16*)d_in[3],
      W1, W1, DDIM, DDIM, DDIM, DDIM);
  gemm_bt<float, float, bf16, 2><<<dim3(16, 64), blk, 0, stream>>>(
      flag, 1, (const float*)d_in[0], (const float*)d_in[2], (const float*)d_in[3],
      W1, W1, DDIM, DDIM, DDIM, DDIM);

  // out = z @ Wout^T + bout -> d_out (nrm dead)
  gemm_bt<bf16, bf16, bf16, 0><<<dim3(16, 64), blk, 0, stream>>>(
      flag, 0, W1, (const bf16*)d_in[13], (const bf16*)d_in[14],
      (bf16*)d_out, nullptr, DDIM, DDIM, DDIM, DDIM);
  gemm_bt<bf16, float, float, 0><<<dim3(16, 64), blk, 0, stream>>>(
      flag, 1, W1, (const float*)d_in[13], (const float*)d_in[14],
      (float*)d_out, nullptr, DDIM, DDIM, DDIM, DDIM);
}

// Round 4
// 819.265 us; speedup vs baseline: 1.0093x; 1.0093x over previous
//
#include <hip/hip_runtime.h>
#include <cstdint>
#include <cstddef>

typedef __bf16 bf16;
typedef __bf16 bf16x8 __attribute__((ext_vector_type(8)));
typedef float f32x4 __attribute__((ext_vector_type(4)));

#define BDIM 4
#define TDIM 2048
#define DDIM 2048
#define HDIM 8
#define DHD 256
#define MTOT 8192
#define NCHUNK 64
#define LCHUNK 32

// async 16B global->LDS; LDS dest = wave-uniform base + lane*16
__device__ __forceinline__ void stage16(const bf16* g, bf16* l) {
  __builtin_amdgcn_global_load_lds(
      (const __attribute__((address_space(1))) void*)g,
      (__attribute__((address_space(3))) void*)l, 16, 0, 0);
}

__device__ __forceinline__ float gelu_tanh(float v) {
  return 0.5f * v * (1.f + tanhf(0.7978845608028654f * (v + 0.044715f * v * v * v)));
}

// ---------------------------------------------------------------------------
// fp32 -> bf16 bulk convert, 8 elem/thread (count must be /2048)
// ---------------------------------------------------------------------------
__global__ __launch_bounds__(256) void f2b(const float* __restrict__ src,
                                           bf16* __restrict__ dst) {
  size_t i = ((size_t)blockIdx.x * 256 + threadIdx.x) * 8;
  const float4 a = *(const float4*)(src + i);
  const float4 b = *(const float4*)(src + i + 4);
  bf16x8 r;
  r[0] = (bf16)a.x; r[1] = (bf16)a.y; r[2] = (bf16)a.z; r[3] = (bf16)a.w;
  r[4] = (bf16)b.x; r[5] = (bf16)b.y; r[6] = (bf16)b.z; r[7] = (bf16)b.w;
  *(bf16x8*)(dst + i) = r;
}

// ---------------------------------------------------------------------------
// C[m,n] = epi(sum_k A[m,k]*B[n,k] + bias[n]); all-bf16 operands, fp32 accum.
// 128x128 tile, BK=32, 4 waves 2x2, 16x16x32 MFMA, global_load_lds width=16
// (m97 structure). EPI: 0 = bias only, 1 = bias + tanh-gelu.  TO = bf16|float
// ---------------------------------------------------------------------------
template <typename TO, int EPI>
__global__ __launch_bounds__(256) void gemm_bt(
    const bf16* __restrict__ A, const bf16* __restrict__ Bm,
    const float* __restrict__ bias, TO* __restrict__ C,
    int K, int lda, int ldb, int ldc) {
  const int n0 = blockIdx.x * 128;
  const int m0 = blockIdx.y * 128;
  __shared__ bf16 As[128 * 32];
  __shared__ bf16 Bs[128 * 32];
  const int tid = threadIdx.x;
  const int lane = tid & 63;
  const int wid = tid >> 6;
  const int waveM = wid >> 1, waveN = wid & 1;
  const int quad = lane >> 4;
  const int l15 = lane & 15;
  const int srow = lane >> 2;        // row within 16-row chunk
  const int scol = (lane & 3) * 8;   // element col octet

  f32x4 acc[4][4];
#pragma unroll
  for (int i = 0; i < 4; ++i)
#pragma unroll
    for (int j = 0; j < 4; ++j)
#pragma unroll
      for (int r = 0; r < 4; ++r) acc[i][j][r] = 0.f;

  for (int k0 = 0; k0 < K; k0 += 32) {
    if (k0) __syncthreads();
#pragma unroll
    for (int cc = 0; cc < 2; ++cc) {
      const int q = wid * 2 + cc;          // chunk 0..7 (16 rows each)
      const int row = q * 16 + srow;
      stage16(A + (size_t)(m0 + row) * lda + k0 + scol, As + q * 512);
      stage16(Bm + (size_t)(n0 + row) * ldb + k0 + scol, Bs + q * 512);
    }
    __syncthreads();
    bf16x8 af[4], bfr[4];
#pragma unroll
    for (int i = 0; i < 4; ++i) {
      af[i]  = *(const bf16x8*)&As[(waveM * 64 + i * 16 + l15) * 32 + quad * 8];
      bfr[i] = *(const bf16x8*)&Bs[(waveN * 64 + i * 16 + l15) * 32 + quad * 8];
    }
#pragma unroll
    for (int i = 0; i < 4; ++i)
#pragma unroll
      for (int j = 0; j < 4; ++j)
        acc[i][j] = __builtin_amdgcn_mfma_f32_16x16x32_bf16(af[i], bfr[j], acc[i][j], 0, 0, 0);
  }

#pragma unroll
  for (int j = 0; j < 4; ++j) {
    const int n = n0 + waveN * 64 + j * 16 + l15;
    const float bv = bias[n];
#pragma unroll
    for (int i = 0; i < 4; ++i) {
#pragma unroll
      for (int r = 0; r < 4; ++r) {
        const int m = m0 + waveM * 64 + i * 16 + quad * 4 + r;
        float v = acc[i][j][r] + bv;
        if (EPI == 1) v = gelu_tanh(v);
        C[(size_t)m * ldc + n] = (TO)v;
      }
    }
  }
}

// ---------------------------------------------------------------------------
// depthwise causal conv, TW=4; bf16 data, fp32 weights
// ---------------------------------------------------------------------------
__global__ __launch_bounds__(256) void conv_kernel(
    const bf16* __restrict__ xp, const float* __restrict__ cw,
    const float* __restrict__ cb, const int* __restrict__ segp,
    bf16* __restrict__ xc) {
  int v = blockIdx.x * 256 + threadIdx.x;
  int dv = v & (DDIM / 8 - 1);
  int m = v >> 8;
  int d0 = dv * 8;
  int t = m & (TDIM - 1);
  int sp = segp[m];
  float acc[8];
#pragma unroll
  for (int j = 0; j < 8; ++j) acc[j] = cb[d0 + j];
#pragma unroll
  for (int i = 0; i < 4; ++i) {
    int shift = 3 - i;
    if (t >= shift && sp >= shift) {
      bf16x8 xv = *(const bf16x8*)&xp[(size_t)(m - shift) * DDIM + d0];
#pragma unroll
      for (int j = 0; j < 8; ++j) acc[j] = fmaf((float)xv[j], cw[i * DDIM + d0 + j], acc[j]);
    }
  }
  bf16x8 o;
#pragma unroll
  for (int j = 0; j < 8; ++j) o[j] = (bf16)acc[j];
  *(bf16x8*)&xc[(size_t)m * DDIM + d0] = o;
}

// ---------------------------------------------------------------------------
// transpose + convert gate weights: dst[h][j][i] = (bf16)src[h][i][j]
// ---------------------------------------------------------------------------
__global__ __launch_bounds__(256) void transpose_gates(
    const float* __restrict__ gxw, const float* __restrict__ gaw,
    bf16* __restrict__ gxT, bf16* __restrict__ gaT) {
  __shared__ bf16 tile[32][33];
  int zz = blockIdx.z;
  int h = zz >> 1;
  const float* src = (zz & 1) ? gaw : gxw;
  bf16* dst = (zz & 1) ? gaT : gxT;
  int j0 = blockIdx.x * 32;
  int i0 = blockIdx.y * 32;
  int r = threadIdx.x >> 5;
  int c = threadIdx.x & 31;
  for (int rr = r; rr < 32; rr += 8)
    tile[rr][c] = (bf16)src[(size_t)(h * DHD + i0 + rr) * DHD + j0 + c];
  __syncthreads();
  for (int rr = r; rr < 32; rr += 8)
    dst[(size_t)(h * DHD + j0 + rr) * DHD + i0 + c] = tile[c][rr];
}

// ---------------------------------------------------------------------------
// fused gate GEMMs (both gates) + RG-LRU epilogue. M=128 x N=256 (full head);
// nrm written in-place over xconv (block exclusively owns its region).
// 512 threads = 8 waves (2M x 4N), register-staged LDS. K = DH = 256.
// ---------------------------------------------------------------------------
__global__ __launch_bounds__(512) void gate_kernel(
    const bf16* __restrict__ xconv,
    const bf16* __restrict__ gxT, const bf16* __restrict__ gaT,
    const float* __restrict__ gxb, const float* __restrict__ gab,
    const float* __restrict__ apar, const int* __restrict__ segp,
    bf16* __restrict__ loga,          // -> xproj slot (dead)
    bf16* __restrict__ nrm) {         // in-place over xconv
  const int m0 = blockIdx.x * 128;
  const int h = blockIdx.y;
  __shared__ bf16 As[128 * 32];
  __shared__ bf16 Bx[256 * 32];
  __shared__ bf16 Ba[256 * 32];
  const int tid = threadIdx.x;
  const int lane = tid & 63;
  const int wid = tid >> 6;
  const int waveM = wid >> 2, waveN = wid & 3;
  const int quad = lane >> 4;
  const int l15 = lane & 15;
  const int r0 = tid >> 2;            // 0..127
  const int cs = (tid & 3) * 8;

  const bf16* baseA = xconv + (size_t)(m0 + r0) * DDIM + h * DHD + cs;
  const bf16* baseX = gxT + (size_t)h * DHD * DHD + cs;
  const bf16* baseB = gaT + (size_t)h * DHD * DHD + cs;

  f32x4 accx[4][4], acca[4][4];
#pragma unroll
  for (int i = 0; i < 4; ++i)
#pragma unroll
    for (int j = 0; j < 4; ++j)
#pragma unroll
      for (int r = 0; r < 4; ++r) { accx[i][j][r] = 0.f; acca[i][j][r] = 0.f; }

  bf16x8 gA, gX0, gX1, gB0, gB1;
#define GATE_LOAD(kk)                                                     \
  do {                                                                    \
    gA  = *(const bf16x8*)&baseA[(kk)];                                   \
    gX0 = *(const bf16x8*)&baseX[(size_t)r0 * DHD + (kk)];                \
    gX1 = *(const bf16x8*)&baseX[(size_t)(r0 + 128) * DHD + (kk)];        \
    gB0 = *(const bf16x8*)&baseB[(size_t)r0 * DHD + (kk)];                \
    gB1 = *(const bf16x8*)&baseB[(size_t)(r0 + 128) * DHD + (kk)];        \
  } while (0)

  GATE_LOAD(0);
  for (int k0 = 0; k0 < DHD; k0 += 32) {
    if (k0) __syncthreads();
    *(bf16x8*)&As[r0 * 32 + cs] = gA;
    *(bf16x8*)&Bx[r0 * 32 + cs] = gX0;
    *(bf16x8*)&Bx[(r0 + 128) * 32 + cs] = gX1;
    *(bf16x8*)&Ba[r0 * 32 + cs] = gB0;
    *(bf16x8*)&Ba[(r0 + 128) * 32 + cs] = gB1;
    const int kn = k0 + 32;
    if (kn < DHD) GATE_LOAD(kn);
    __syncthreads();
    bf16x8 af[4];
#pragma unroll
    for (int i = 0; i < 4; ++i)
      af[i] = *(const bf16x8*)&As[(waveM * 64 + i * 16 + l15) * 32 + quad * 8];
#pragma unroll
    for (int j = 0; j < 4; ++j) {
      bf16x8 bx = *(const bf16x8*)&Bx[(waveN * 64 + j * 16 + l15) * 32 + quad * 8];
      bf16x8 ba = *(const bf16x8*)&Ba[(waveN * 64 + j * 16 + l15) * 32 + quad * 8];
#pragma unroll
      for (int i = 0; i < 4; ++i) {
        accx[i][j] = __builtin_amdgcn_mfma_f32_16x16x32_bf16(af[i], bx, accx[i][j], 0, 0, 0);
        acca[i][j] = __builtin_amdgcn_mfma_f32_16x16x32_bf16(af[i], ba, acca[i][j], 0, 0, 0);
      }
    }
  }
#undef GATE_LOAD

#pragma unroll
  for (int j = 0; j < 4; ++j) {
    const int jj = waveN * 64 + j * 16 + l15;
    const int d = h * DHD + jj;
    const float bxv = gxb[h * DHD + jj];
    const float bav = gab[h * DHD + jj];
    const float sp = log1pf(expf(apar[d]));
#pragma unroll
    for (int i = 0; i < 4; ++i) {
#pragma unroll
      for (int r = 0; r < 4; ++r) {
        const int m = m0 + waveM * 64 + i * 16 + quad * 4 + r;
        const float gx = 1.f / (1.f + expf(-(accx[i][j][r] + bxv)));
        const float ga = 1.f / (1.f + expf(-(acca[i][j][r] + bav)));
        const float log_a = -8.f * ga * sp;
        const bool reset = (segp[m] == 0);
        const float mult = reset ? 1.f : sqrtf(fmaxf(1.f - expf(2.f * log_a), 0.f));
        const float xc = (float)xconv[(size_t)m * DDIM + d];
        nrm[(size_t)m * DDIM + d] = (bf16)(xc * gx * mult);
        loga[(size_t)m * DDIM + d] = reset ? (bf16)(-__builtin_inff()) : (bf16)log_a;
      }
    }
  }
}

// ---------------------------------------------------------------------------
// chunked linear scan: h[t] = exp(loga[t])*h[t-1] + nrm[t]
// ---------------------------------------------------------------------------
__global__ __launch_bounds__(256) void scan_phase1(
    const bf16* __restrict__ loga, const bf16* __restrict__ nrm,
    float* __restrict__ chA, float* __restrict__ chH) {
  int idx = blockIdx.x * 256 + threadIdx.x;
  int d = idx & (DDIM - 1);
  int c = (idx >> 11) & (NCHUNK - 1);
  int b = idx >> 17;
  size_t base = (size_t)(b * TDIM + c * LCHUNK) * DDIM + d;
  float A = 1.f, hh = 0.f;
#pragma unroll 4
  for (int i = 0; i < LCHUNK; ++i) {
    size_t o = base + (size_t)i * DDIM;
    float a = expf((float)loga[o]);
    hh = fmaf(a, hh, (float)nrm[o]);
    A *= a;
  }
  int ci = (b * NCHUNK + c) * DDIM + d;
  chA[ci] = A;
  chH[ci] = hh;
}

__global__ __launch_bounds__(256) void scan_phase2(
    const float* __restrict__ chA, const float* __restrict__ chH,
    float* __restrict__ hst) {
  int idx = blockIdx.x * 256 + threadIdx.x;
  int d = idx & (DDIM - 1);
  int b = idx >> 11;
  float s = 0.f;
  for (int c = 0; c < NCHUNK; ++c) {
    int ci = (b * NCHUNK + c) * DDIM + d;
    hst[ci] = s;
    s = fmaf(chA[ci], s, chH[ci]);
  }
}

// z = h * y, written in-place over y (same-index elementwise)
__global__ __launch_bounds__(256) void scan_phase3(
    const bf16* __restrict__ loga, const bf16* __restrict__ nrm,
    const float* __restrict__ hst, bf16* __restrict__ yz) {
  int idx = blockIdx.x * 256 + threadIdx.x;
  int d = idx & (DDIM - 1);
  int c = (idx >> 11) & (NCHUNK - 1);
  int b = idx >> 17;
  size_t base = (size_t)(b * TDIM + c * LCHUNK) * DDIM + d;
  float hh = hst[(b * NCHUNK + c) * DDIM + d];
#pragma unroll 4
  for (int i = 0; i < LCHUNK; ++i) {
    size_t o = base + (size_t)i * DDIM;
    float a = expf((float)loga[o]);
    hh = fmaf(a, hh, (float)nrm[o]);
    yz[o] = (bf16)(hh * (float)yz[o]);
  }
}

// ---------------------------------------------------------------------------
extern "C" void kernel_launch(void* const* d_in, const int* in_sizes, int n_in,
                              void* d_out, int out_size, void* d_ws, size_t ws_size,
                              hipStream_t stream) {
  const float* x    = (const float*)d_in[0];
  const int*   segp = (const int*)d_in[1];
  const float* Wy   = (const float*)d_in[2];
  const float* by   = (const float*)d_in[3];
  const float* Wx   = (const float*)d_in[4];
  const float* bx   = (const float*)d_in[5];
  const float* cw   = (const float*)d_in[6];
  const float* cb   = (const float*)d_in[7];
  const float* gxw  = (const float*)d_in[8];
  const float* gxb  = (const float*)d_in[9];
  const float* gaw  = (const float*)d_in[10];
  const float* gab  = (const float*)d_in[11];
  const float* apar = (const float*)d_in[12];
  const float* Wout = (const float*)d_in[13];
  const float* bout = (const float*)d_in[14];

  const size_t MD = (size_t)MTOT * DDIM;      // 16.78M elements
  const size_t WD = (size_t)DDIM * DDIM;      // 4.19M elements
  // d_out (fp32, 67 MB) doubles as bf16 scratch until the final GEMM:
  bf16* xb    = (bf16*)d_out;                  // lower 33.5 MB: xb -> xconv/nrm
  bf16* xproj = (bf16*)((char*)d_out + MD * 2);// upper 33.5 MB: xproj -> loga
  bf16* xconv = xb;
  bf16* nrm   = xb;
  bf16* loga  = xproj;

  // ws (~58 MB): WB1 | WB2 | W1 | gxT | gaT | chA | chH | hst
  char* ws = (char*)d_ws;
  bf16*  WB1 = (bf16*)ws;                       // Wxb, later Woutb (8.4 MB)
  bf16*  WB2 = (bf16*)(ws + WD * 2);            // Wyb (8.4 MB)
  bf16*  W1  = (bf16*)(ws + 2 * WD * 2);        // y -> z (33.5 MB)
  char*  tail = ws + 2 * WD * 2 + MD * 2;
  const size_t GW = (size_t)HDIM * DHD * DHD * 2;  // 1 MiB
  const size_t CH = (size_t)BDIM * NCHUNK * DDIM * 4;  // 2 MiB
  bf16*  gxT = (bf16*)tail;
  bf16*  gaT = (bf16*)(tail + GW);
  float* chA = (float*)(tail + 2 * GW);
  float* chH = (float*)(tail + 2 * GW + CH);
  float* hst = (float*)(tail + 2 * GW + 2 * CH);

  dim3 blk(256);
  // fp32 -> bf16 conversions
  f2b<<<dim3(MD / 2048), blk, 0, stream>>>(x, xb);
  f2b<<<dim3(WD / 2048), blk, 0, stream>>>(Wx, WB1);
  f2b<<<dim3(WD / 2048), blk, 0, stream>>>(Wy, WB2);
  transpose_gates<<<dim3(8, 8, 16), blk, 0, stream>>>(gxw, gaw, gxT, gaT);

  // xproj = x @ Wx^T + bx ; y = gelu(x @ Wy^T + by)
  gemm_bt<bf16, 0><<<dim3(16, 64), blk, 0, stream>>>(xb, WB1, bx, xproj, DDIM, DDIM, DDIM, DDIM);
  gemm_bt<bf16, 1><<<dim3(16, 64), blk, 0, stream>>>(xb, WB2, by, W1, DDIM, DDIM, DDIM, DDIM);

  // xconv (in-place over xb; reads xproj) -- xb dead after the two GEMMs
  conv_kernel<<<dim3(MTOT * (DDIM / 8) / 256), blk, 0, stream>>>(xproj, cw, cb, segp, xconv);

  // gates + RG-LRU elementwise: nrm over xconv, loga over xproj
  gate_kernel<<<dim3(64, 8), dim3(512), 0, stream>>>(xconv, gxT, gaT, gxb, gab, apar, segp, loga, nrm);

  // scan; phase3 writes z = h*y in-place over y (W1)
  scan_phase1<<<dim3(BDIM * NCHUNK * DDIM / 256), blk, 0, stream>>>(loga, nrm, chA, chH);
  scan_phase2<<<dim3(BDIM * DDIM / 256), blk, 0, stream>>>(chA, chH, hst);
  scan_phase3<<<dim3(BDIM * NCHUNK * DDIM / 256), blk, 0, stream>>>(loga, nrm, hst, W1);

  // out = z @ Wout^T + bout  (fp32 write over all of d_out; scratch dead)
  f2b<<<dim3(WD / 2048), blk, 0, stream>>>(Wout, WB1);
  gemm_bt<float, 0><<<dim3(16, 64), blk, 0, stream>>>(W1, WB1, bout, (float*)d_out, DDIM, DDIM, DDIM, DDIM);
}

// Round 6
// 659.995 us; speedup vs baseline: 1.2528x; 1.2413x over previous
//
#include <hip/hip_runtime.h>
#include <cstdint>
#include <cstddef>

typedef __bf16 bf16;
typedef __bf16 bf16x8 __attribute__((ext_vector_type(8)));
typedef float f32x4 __attribute__((ext_vector_type(4)));

#define BDIM 4
#define TDIM 2048
#define DDIM 2048
#define HDIM 8
#define DHD 256
#define MTOT 8192
#define NCHUNK 64
#define LCHUNK 32

// async 16B global->LDS; LDS dest = wave-uniform base + lane*16
__device__ __forceinline__ void stage16(const bf16* g, bf16* l) {
  __builtin_amdgcn_global_load_lds(
      (const __attribute__((address_space(1))) void*)g,
      (__attribute__((address_space(3))) void*)l, 16, 0, 0);
}

__device__ __forceinline__ float sigmoid_f(float x) {
  return __fdividef(1.f, 1.f + __expf(-x));
}
__device__ __forceinline__ float gelu_tanh(float v) {
  float u = 0.7978845608028654f * (v + 0.044715f * v * v * v);
  u = fminf(fmaxf(u, -15.f), 15.f);
  float t = __expf(2.f * u);                       // tanh(u) = (t-1)/(t+1)
  return 0.5f * v * (1.f + __fdividef(t - 1.f, t + 1.f));
}
__device__ __forceinline__ float softplus_f(float x) {
  return __logf(1.f + __expf(x));                  // x in [-1.2, 0.4] here
}

// ---------------------------------------------------------------------------
// fp32 -> bf16 bulk convert, 8 elem/thread (count must be /2048)
// ---------------------------------------------------------------------------
__global__ __launch_bounds__(256) void f2b(const float* __restrict__ src,
                                           bf16* __restrict__ dst) {
  size_t i = ((size_t)blockIdx.x * 256 + threadIdx.x) * 8;
  const float4 a = *(const float4*)(src + i);
  const float4 b = *(const float4*)(src + i + 4);
  bf16x8 r;
  r[0] = (bf16)a.x; r[1] = (bf16)a.y; r[2] = (bf16)a.z; r[3] = (bf16)a.w;
  r[4] = (bf16)b.x; r[5] = (bf16)b.y; r[6] = (bf16)b.z; r[7] = (bf16)b.w;
  *(bf16x8*)(dst + i) = r;
}

// ---------------------------------------------------------------------------
// C[m,n] = epi(sum_k A[m,k]*B[n,k] + bias[n]); all-bf16 operands, fp32 accum.
// 128x128 tile, BK=32, 4 waves 2x2, 16x16x32 MFMA, global_load_lds width=16.
// EPI: 0 = bias only, 1 = bias + tanh-gelu.  TO = bf16|float
// ---------------------------------------------------------------------------
template <typename TO, int EPI>
__global__ __launch_bounds__(256) void gemm_bt(
    const bf16* __restrict__ A, const bf16* __restrict__ Bm,
    const float* __restrict__ bias, TO* __restrict__ C,
    int K, int lda, int ldb, int ldc) {
  const int n0 = blockIdx.x * 128;
  const int m0 = blockIdx.y * 128;
  __shared__ bf16 As[128 * 32];
  __shared__ bf16 Bs[128 * 32];
  const int tid = threadIdx.x;
  const int lane = tid & 63;
  const int wid = tid >> 6;
  const int waveM = wid >> 1, waveN = wid & 1;
  const int quad = lane >> 4;
  const int l15 = lane & 15;
  const int srow = lane >> 2;
  const int scol = (lane & 3) * 8;

  f32x4 acc[4][4];
#pragma unroll
  for (int i = 0; i < 4; ++i)
#pragma unroll
    for (int j = 0; j < 4; ++j)
#pragma unroll
      for (int r = 0; r < 4; ++r) acc[i][j][r] = 0.f;

  for (int k0 = 0; k0 < K; k0 += 32) {
    if (k0) __syncthreads();
#pragma unroll
    for (int cc = 0; cc < 2; ++cc) {
      const int q = wid * 2 + cc;
      const int row = q * 16 + srow;
      stage16(A + (size_t)(m0 + row) * lda + k0 + scol, As + q * 512);
      stage16(Bm + (size_t)(n0 + row) * ldb + k0 + scol, Bs + q * 512);
    }
    __syncthreads();
    bf16x8 af[4], bfr[4];
#pragma unroll
    for (int i = 0; i < 4; ++i) {
      af[i]  = *(const bf16x8*)&As[(waveM * 64 + i * 16 + l15) * 32 + quad * 8];
      bfr[i] = *(const bf16x8*)&Bs[(waveN * 64 + i * 16 + l15) * 32 + quad * 8];
    }
#pragma unroll
    for (int i = 0; i < 4; ++i)
#pragma unroll
      for (int j = 0; j < 4; ++j)
        acc[i][j] = __builtin_amdgcn_mfma_f32_16x16x32_bf16(af[i], bfr[j], acc[i][j], 0, 0, 0);
  }

#pragma unroll
  for (int j = 0; j < 4; ++j) {
    const int n = n0 + waveN * 64 + j * 16 + l15;
    const float bv = bias[n];
#pragma unroll
    for (int i = 0; i < 4; ++i) {
#pragma unroll
      for (int r = 0; r < 4; ++r) {
        const int m = m0 + waveM * 64 + i * 16 + quad * 4 + r;
        float v = acc[i][j][r] + bv;
        if (EPI == 1) v = gelu_tanh(v);
        C[(size_t)m * ldc + n] = (TO)v;
      }
    }
  }
}

// ---------------------------------------------------------------------------
// gate pre-activation GEMM: one gate per block (z = h*2+g), 128x128 tile,
// K = DH = 256. out[m, h*DHD + n] = sum_k xconv[m, h*DHD+k] * W[g][h][n][k]
// (bias folded into the scan's elementwise recompute).
// ---------------------------------------------------------------------------
__global__ __launch_bounds__(256) void gate_gemm(
    const bf16* __restrict__ xconv,
    const bf16* __restrict__ gxT, const bf16* __restrict__ gaT,
    bf16* __restrict__ gxr, bf16* __restrict__ gar) {
  const int h = blockIdx.z >> 1;
  const int g = blockIdx.z & 1;
  const bf16* A = xconv + h * DHD;                       // lda = DDIM
  const bf16* Bm = (g ? gaT : gxT) + (size_t)h * DHD * DHD;  // ldb = DHD
  bf16* C = (g ? gar : gxr) + h * DHD;                   // ldc = DDIM
  const int n0 = blockIdx.x * 128;
  const int m0 = blockIdx.y * 128;
  __shared__ bf16 As[128 * 32];
  __shared__ bf16 Bs[128 * 32];
  const int tid = threadIdx.x;
  const int lane = tid & 63;
  const int wid = tid >> 6;
  const int waveM = wid >> 1, waveN = wid & 1;
  const int quad = lane >> 4;
  const int l15 = lane & 15;
  const int srow = lane >> 2;
  const int scol = (lane & 3) * 8;

  f32x4 acc[4][4];
#pragma unroll
  for (int i = 0; i < 4; ++i)
#pragma unroll
    for (int j = 0; j < 4; ++j)
#pragma unroll
      for (int r = 0; r < 4; ++r) acc[i][j][r] = 0.f;

  for (int k0 = 0; k0 < DHD; k0 += 32) {
    if (k0) __syncthreads();
#pragma unroll
    for (int cc = 0; cc < 2; ++cc) {
      const int q = wid * 2 + cc;
      const int row = q * 16 + srow;
      stage16(A + (size_t)(m0 + row) * DDIM + k0 + scol, As + q * 512);
      stage16(Bm + (size_t)(n0 + row) * DHD + k0 + scol, Bs + q * 512);
    }
    __syncthreads();
    bf16x8 af[4], bfr[4];
#pragma unroll
    for (int i = 0; i < 4; ++i) {
      af[i]  = *(const bf16x8*)&As[(waveM * 64 + i * 16 + l15) * 32 + quad * 8];
      bfr[i] = *(const bf16x8*)&Bs[(waveN * 64 + i * 16 + l15) * 32 + quad * 8];
    }
#pragma unroll
    for (int i = 0; i < 4; ++i)
#pragma unroll
      for (int j = 0; j < 4; ++j)
        acc[i][j] = __builtin_amdgcn_mfma_f32_16x16x32_bf16(af[i], bfr[j], acc[i][j], 0, 0, 0);
  }

#pragma unroll
  for (int j = 0; j < 4; ++j) {
    const int n = n0 + waveN * 64 + j * 16 + l15;
#pragma unroll
    for (int i = 0; i < 4; ++i) {
#pragma unroll
      for (int r = 0; r < 4; ++r) {
        const int m = m0 + waveM * 64 + i * 16 + quad * 4 + r;
        C[(size_t)m * DDIM + n] = (bf16)acc[i][j][r];
      }
    }
  }
}

// ---------------------------------------------------------------------------
// depthwise causal conv, TW=4; bf16 data, fp32 weights
// ---------------------------------------------------------------------------
__global__ __launch_bounds__(256) void conv_kernel(
    const bf16* __restrict__ xp, const float* __restrict__ cw,
    const float* __restrict__ cb, const int* __restrict__ segp,
    bf16* __restrict__ xc) {
  int v = blockIdx.x * 256 + threadIdx.x;
  int dv = v & (DDIM / 8 - 1);
  int m = v >> 8;
  int d0 = dv * 8;
  int t = m & (TDIM - 1);
  int sp = segp[m];
  float acc[8];
#pragma unroll
  for (int j = 0; j < 8; ++j) acc[j] = cb[d0 + j];
#pragma unroll
  for (int i = 0; i < 4; ++i) {
    int shift = 3 - i;
    if (t >= shift && sp >= shift) {
      bf16x8 xv = *(const bf16x8*)&xp[(size_t)(m - shift) * DDIM + d0];
#pragma unroll
      for (int j = 0; j < 8; ++j) acc[j] = fmaf((float)xv[j], cw[i * DDIM + d0 + j], acc[j]);
    }
  }
  bf16x8 o;
#pragma unroll
  for (int j = 0; j < 8; ++j) o[j] = (bf16)acc[j];
  *(bf16x8*)&xc[(size_t)m * DDIM + d0] = o;
}

// ---------------------------------------------------------------------------
// transpose + convert gate weights: dst[h][j][i] = (bf16)src[h][i][j]
// ---------------------------------------------------------------------------
__global__ __launch_bounds__(256) void transpose_gates(
    const float* __restrict__ gxw, const float* __restrict__ gaw,
    bf16* __restrict__ gxT, bf16* __restrict__ gaT) {
  __shared__ bf16 tile[32][33];
  int zz = blockIdx.z;
  int h = zz >> 1;
  const float* src = (zz & 1) ? gaw : gxw;
  bf16* dst = (zz & 1) ? gaT : gxT;
  int j0 = blockIdx.x * 32;
  int i0 = blockIdx.y * 32;
  int r = threadIdx.x >> 5;
  int c = threadIdx.x & 31;
  for (int rr = r; rr < 32; rr += 8)
    tile[rr][c] = (bf16)src[(size_t)(h * DHD + i0 + rr) * DHD + j0 + c];
  __syncthreads();
  for (int rr = r; rr < 32; rr += 8)
    dst[(size_t)(h * DHD + j0 + rr) * DHD + i0 + c] = tile[c][rr];
}

// ---------------------------------------------------------------------------
// RG-LRU elementwise recompute, shared by scan phases
// ---------------------------------------------------------------------------
__device__ __forceinline__ void lru_elem(float pgx, float pga, float xc,
                                         float spv, bool reset,
                                         float& a, float& nr) {
  const float gx = sigmoid_f(pgx);
  const float ga = sigmoid_f(pga);
  const float la = -8.f * ga * spv;
  a = reset ? 0.f : __expf(la);
  const float mult = reset ? 1.f : sqrtf(fmaxf(1.f - __expf(2.f * la), 0.f));
  nr = xc * gx * mult;
}

// chunked scan phase 1: per (b, chunk, d) compute prod(a) and h across chunk
__global__ __launch_bounds__(256) void scan_phase1(
    const bf16* __restrict__ gxr, const bf16* __restrict__ gar,
    const bf16* __restrict__ xconv,
    const float* __restrict__ gxb, const float* __restrict__ gab,
    const float* __restrict__ apar, const int* __restrict__ segp,
    float* __restrict__ chA, float* __restrict__ chH) {
  int idx = blockIdx.x * 256 + threadIdx.x;
  int d = idx & (DDIM - 1);
  int c = (idx >> 11) & (NCHUNK - 1);
  int b = idx >> 17;
  const float gxbv = gxb[d], gabv = gab[d];
  const float spv = softplus_f(apar[d]);
  const int mrow = b * TDIM + c * LCHUNK;
  size_t base = (size_t)mrow * DDIM + d;
  float A = 1.f, hh = 0.f;
  for (int i = 0; i < LCHUNK; ++i) {
    size_t o = base + (size_t)i * DDIM;
    float a, nr;
    lru_elem((float)gxr[o] + gxbv, (float)gar[o] + gabv, (float)xconv[o],
             spv, segp[mrow + i] == 0, a, nr);
    hh = fmaf(a, hh, nr);
    A *= a;
  }
  int ci = (b * NCHUNK + c) * DDIM + d;
  chA[ci] = A;
  chH[ci] = hh;
}

__global__ __launch_bounds__(256) void scan_phase2(
    const float* __restrict__ chA, const float* __restrict__ chH,
    float* __restrict__ hst) {
  int idx = blockIdx.x * 256 + threadIdx.x;
  int d = idx & (DDIM - 1);
  int b = idx >> 11;
  float s = 0.f;
  for (int c = 0; c < NCHUNK; ++c) {
    int ci = (b * NCHUNK + c) * DDIM + d;
    hst[ci] = s;
    s = fmaf(chA[ci], s, chH[ci]);
  }
}

// phase 3: replay scan with chunk-start state; z = h*y in-place over y
__global__ __launch_bounds__(256) void scan_phase3(
    const bf16* __restrict__ gxr, const bf16* __restrict__ gar,
    const bf16* __restrict__ xconv,
    const float* __restrict__ gxb, const float* __restrict__ gab,
    const float* __restrict__ apar, const int* __restrict__ segp,
    const float* __restrict__ hst, bf16* __restrict__ yz) {
  int idx = blockIdx.x * 256 + threadIdx.x;
  int d = idx & (DDIM - 1);
  int c = (idx >> 11) & (NCHUNK - 1);
  int b = idx >> 17;
  const float gxbv = gxb[d], gabv = gab[d];
  const float spv = softplus_f(apar[d]);
  const int mrow = b * TDIM + c * LCHUNK;
  size_t base = (size_t)mrow * DDIM + d;
  float hh = hst[(b * NCHUNK + c) * DDIM + d];
  for (int i = 0; i < LCHUNK; ++i) {
    size_t o = base + (size_t)i * DDIM;
    float a, nr;
    lru_elem((float)gxr[o] + gxbv, (float)gar[o] + gabv, (float)xconv[o],
             spv, segp[mrow + i] == 0, a, nr);
    hh = fmaf(a, hh, nr);
    yz[o] = (bf16)(hh * (float)yz[o]);
  }
}

// ---------------------------------------------------------------------------
extern "C" void kernel_launch(void* const* d_in, const int* in_sizes, int n_in,
                              void* d_out, int out_size, void* d_ws, size_t ws_size,
                              hipStream_t stream) {
  const float* x    = (const float*)d_in[0];
  const int*   segp = (const int*)d_in[1];
  const float* Wy   = (const float*)d_in[2];
  const float* by   = (const float*)d_in[3];
  const float* Wx   = (const float*)d_in[4];
  const float* bx   = (const float*)d_in[5];
  const float* cw   = (const float*)d_in[6];
  const float* cb   = (const float*)d_in[7];
  const float* gxw  = (const float*)d_in[8];
  const float* gxb  = (const float*)d_in[9];
  const float* gaw  = (const float*)d_in[10];
  const float* gab  = (const float*)d_in[11];
  const float* apar = (const float*)d_in[12];
  const float* Wout = (const float*)d_in[13];
  const float* bout = (const float*)d_in[14];

  const size_t MD = (size_t)MTOT * DDIM;       // 16.78M elements
  const size_t WD = (size_t)DDIM * DDIM;       // 4.19M elements
  // d_out (fp32, 67 MB) as bf16 scratch until the final GEMM:
  bf16* xb    = (bf16*)d_out;                   // lower: xb -> xconv
  bf16* xproj = (bf16*)((char*)d_out + MD * 2); // upper: xproj -> gxr
  bf16* xconv = xb;
  bf16* gxr   = xproj;

  // ws (~92 MB): gar | W1 | WB1 | WB2 | gxT | gaT | chA | chH | hst
  char* ws = (char*)d_ws;
  bf16*  gar = (bf16*)ws;                        // 33.5 MB
  bf16*  W1  = (bf16*)(ws + MD * 2);             // y -> z (33.5 MB)
  bf16*  WB1 = (bf16*)(ws + 2 * MD * 2);         // Wxb, later Woutb (8.4 MB)
  bf16*  WB2 = (bf16*)(ws + 2 * MD * 2 + WD * 2);// Wyb (8.4 MB)
  char*  tail = ws + 2 * MD * 2 + 2 * WD * 2;
  const size_t GW = (size_t)HDIM * DHD * DHD * 2;      // 1 MiB
  const size_t CH = (size_t)BDIM * NCHUNK * DDIM * 4;  // 2 MiB
  bf16*  gxT = (bf16*)tail;
  bf16*  gaT = (bf16*)(tail + GW);
  float* chA = (float*)(tail + 2 * GW);
  float* chH = (float*)(tail + 2 * GW + CH);
  float* hst = (float*)(tail + 2 * GW + 2 * CH);

  dim3 blk(256);
  f2b<<<dim3(MD / 2048), blk, 0, stream>>>(x, xb);
  f2b<<<dim3(WD / 2048), blk, 0, stream>>>(Wx, WB1);
  f2b<<<dim3(WD / 2048), blk, 0, stream>>>(Wy, WB2);
  transpose_gates<<<dim3(8, 8, 16), blk, 0, stream>>>(gxw, gaw, gxT, gaT);

  // xproj = x @ Wx^T + bx ; y = gelu(x @ Wy^T + by)
  gemm_bt<bf16, 0><<<dim3(16, 64), blk, 0, stream>>>(xb, WB1, bx, xproj, DDIM, DDIM, DDIM, DDIM);
  gemm_bt<bf16, 1><<<dim3(16, 64), blk, 0, stream>>>(xb, WB2, by, W1, DDIM, DDIM, DDIM, DDIM);

  // xconv in-place over xb (reads xproj; xb dead after the two GEMMs)
  conv_kernel<<<dim3(MTOT * (DDIM / 8) / 256), blk, 0, stream>>>(xproj, cw, cb, segp, xconv);

  // gate pre-activations: gxr over xproj (dead), gar in ws
  // N-extent = DHD = 256 -> TWO 128-wide column tiles (grid.x = 2)!
  gate_gemm<<<dim3(2, 64, 16), blk, 0, stream>>>(xconv, gxT, gaT, gxr, gar);

  // chunked scan with fused RG-LRU elementwise; phase3 writes z = h*y over y
  scan_phase1<<<dim3(BDIM * NCHUNK * DDIM / 256), blk, 0, stream>>>(
      gxr, gar, xconv, gxb, gab, apar, segp, chA, chH);
  scan_phase2<<<dim3(BDIM * DDIM / 256), blk, 0, stream>>>(chA, chH, hst);
  scan_phase3<<<dim3(BDIM * NCHUNK * DDIM / 256), blk, 0, stream>>>(
      gxr, gar, xconv, gxb, gab, apar, segp, hst, W1);

  // out = z @ Wout^T + bout (fp32 over all of d_out; scratch dead)
  f2b<<<dim3(WD / 2048), blk, 0, stream>>>(Wout, WB1);
  gemm_bt<float, 0><<<dim3(16, 64), blk, 0, stream>>>(W1, WB1, bout, (float*)d_out, DDIM, DDIM, DDIM, DDIM);
}